// Round 16
// baseline (77.793 us; speedup 1.0000x reference)
//
#include <hip/hip_runtime.h>

#define BATCH 16
#define HH 512
#define WW 512
#define PLANE (HH*WW)

// Compiler memory-order fences for wave-synchronous LDS exchange.
#define LDS_WAIT()   asm volatile("s_waitcnt lgkmcnt(0)" ::: "memory")
#define WAVE_FENCE() asm volatile("" ::: "memory")

// bf16 pair helpers: word = x in low 16 bits, y in high 16 bits
__device__ __forceinline__ float bf_lo(unsigned u) {
    union { unsigned u; float f; } c; c.u = u << 16; return c.f;
}
__device__ __forceinline__ float bf_hi(unsigned u) {
    union { unsigned u; float f; } c; c.u = u & 0xFFFF0000u; return c.f;
}
__device__ __forceinline__ unsigned f2bf(float f) {   // RTNE, returns low-16 bf16
    union { float f; unsigned u; } c; c.f = f;
    return (c.u + 0x7FFFu + ((c.u >> 16) & 1u)) >> 16;
}
__device__ __forceinline__ unsigned packbf(float x, float y) {
    return f2bf(x) | (f2bf(y) << 16);
}
__device__ __forceinline__ float min3f(float a, float b, float c) {
    return fminf(fminf(a, b), c);    // clang fuses to v_min3_f32
}
__device__ __forceinline__ float4 add4(float4 a, float4 b) {
    return make_float4(a.x+b.x, a.y+b.y, a.z+b.z, a.w+b.w);
}
// balanced-tree 15-tap sum over float4 slots: 15 x ds_read_b128
__device__ __forceinline__ float4 tsum15v(const float4* p) {
    float4 s = add4(add4(add4(p[0],p[1]),add4(p[2],p[3])),
                    add4(add4(p[4],p[5]),add4(p[6],p[7])));
    float4 u = add4(add4(add4(p[8],p[9]),add4(p[10],p[11])),
                    add4(add4(p[12],p[13]),p[14]));
    return add4(s, u);
}

// ---------------- K1: guide (channel mean) + 15x15 replicate min-pool -> packed bf16 (g,p) ----------------
#define T1 64
#define HALO 7
#define LW (T1 + 2*HALO)   // 78

__global__ __launch_bounds__(256) void k1_guide_minpool(
    const float* __restrict__ smoky, unsigned* __restrict__ gp)
{
    __shared__ float dcp[LW*LW];          // per-pixel channel min, with replicate halo
    __shared__ float vmn[T1*LW];          // vertical 15-min
    __shared__ unsigned short gsh[T1*T1]; // guide (bf16) for interior
    int nwg = gridDim.x;             // 1024, divisible by 8
    int wg = (blockIdx.x & 7) * (nwg >> 3) + (blockIdx.x >> 3);  // XCD-chunked swizzle
    int img  = wg >> 6;              // 64 tiles per image
    int tile = wg & 63;
    int y0 = (tile >> 3) * T1;
    int x0 = (tile & 7) * T1;
    int t = threadIdx.x;
    const float* s0 = smoky + (size_t)img * 3 * PLANE;
    unsigned* gpl = gp + (size_t)img * PLANE;

    for (int i = t; i < LW*LW; i += 256) {
        int ly = i / LW, lx = i - ly * LW;
        int iy = y0 - HALO + ly, ix = x0 - HALO + lx;
        int cy = min(max(iy, 0), HH-1);
        int cx = min(max(ix, 0), WW-1);
        const float* bp = s0 + cy * WW + cx;
        float c0 = bp[0], c1 = bp[PLANE], c2 = bp[2*PLANE];
        dcp[i] = min3f(c0, c1, c2);
        if (ly >= HALO && ly < HALO+T1 && lx >= HALO && lx < HALO+T1)
            gsh[(ly-HALO)*T1 + (lx-HALO)] = (unsigned short)f2bf((c0 + c1 + c2) * (1.0f/3.0f));
    }
    __syncthreads();
    for (int i = t; i < T1*LW; i += 256) {
        int r = i / LW, c = i - r * LW;
        const float* q = &dcp[r*LW + c];
        float m = min3f(min3f(min3f(q[0*LW],q[1*LW],q[2*LW]),
                              min3f(q[3*LW],q[4*LW],q[5*LW]),
                              min3f(q[6*LW],q[7*LW],q[8*LW])),
                        min3f(q[9*LW],q[10*LW],q[11*LW]),
                        min3f(q[12*LW],q[13*LW],q[14*LW]));
        vmn[i] = m;
    }
    __syncthreads();
    for (int i = t; i < T1*T1; i += 256) {
        int r = i >> 6, c = i & 63;
        const float* q = &vmn[r*LW + c];
        float m = min3f(min3f(min3f(q[0],q[1],q[2]),
                              min3f(q[3],q[4],q[5]),
                              min3f(q[6],q[7],q[8])),
                        min3f(q[9],q[10],q[11]),
                        min3f(q[12],q[13],q[14]));
        gpl[(y0+r)*WW + x0 + c] = (unsigned)gsh[r*T1+c] | (f2bf(m) << 16);
    }
}

// ================= K2: pair-row sliding box sums, quantity-packed float4 exchange =================
#define RS2 16

__global__ __launch_bounds__(256) void k2_ab(
    const unsigned* __restrict__ gp, unsigned* __restrict__ abO)
{
    __shared__ float4 ls[4][2][80];   // [wave][row e/o][slot] slot=(sI,sII,sP,sIp)
    int nwg = gridDim.x;             // 1024
    int wg = (blockIdx.x & 7) * (nwg >> 3) + (blockIdx.x >> 3);
    int w = threadIdx.x >> 6, l = threadIdx.x & 63;
    int gw = wg * 4 + w;             // 0..4095
    int img   = gw >> 8;             // 256 waves per image
    int cg    = (gw >> 5) & 7;
    int strip = gw & 31;
    int y0 = strip * RS2;
    int c0 = cg * 64;
    const unsigned* gpP = gp + (size_t)img * PLANE;
    unsigned* abP = abO + (size_t)img * PLANE;

    int col0 = c0 - 7 + l;      // slot l
    int col1 = c0 + 57 + l;     // slot 64+l (lanes 0..13)
    bool v0 = (col0 >= 0);
    bool v1 = (l < 14) && (col1 < WW);

    float sI0=0,sII0=0,sP0=0,sIp0=0;
    float sI1=0,sII1=0,sP1=0,sIp1=0;

    auto loadrow = [&](int y, unsigned& u0, unsigned& u1) {
        int yc = min(max(y, 0), HH-1);
        const unsigned* r = gpP + (size_t)yc * WW;
        unsigned a = 0u, b = 0u;
        if (v0) a = r[col0];
        if (v1) b = r[col1];
        bool rv = ((unsigned)y < (unsigned)HH);
        u0 = rv ? a : 0u;
        u1 = rv ? b : 0u;
    };

    // warm-up: window(y0-1) = rows y0-8 .. y0+6
    for (int r = y0 - 8; r <= y0 + 6; ++r) {
        unsigned u0,u1; loadrow(r, u0,u1);
        float g0=bf_lo(u0), p0=bf_hi(u0), g1=bf_lo(u1), p1=bf_hi(u1);
        sI0+=g0; sII0+=g0*g0; sP0+=p0; sIp0+=g0*p0;
        sI1+=g1; sII1+=g1*g1; sP1+=p1; sIp1+=g1*p1;
    }
    unsigned a1M,a1H, s1M,s1H, a2M,a2H, s2M,s2H;
    loadrow(y0 + 7, a1M, a1H);   // add for even row
    loadrow(y0 - 8, s1M, s1H);   // sub for even row
    loadrow(y0 + 8, a2M, a2H);   // add for odd row
    loadrow(y0 - 7, s2M, s2H);   // sub for odd row

    float4* Le = &ls[w][0][0];
    float4* Lo = &ls[w][1][0];
    const float inv225 = 1.0f/225.0f;

    for (int y = y0; y < y0 + RS2; y += 2) {
        // even window y
        {
            float gA=bf_lo(a1M), pA=bf_hi(a1M), gS=bf_lo(s1M), pS=bf_hi(s1M);
            sI0 += gA-gS; sII0 += gA*gA-gS*gS; sP0 += pA-pS; sIp0 += gA*pA-gS*pS;
            float gAh=bf_lo(a1H), pAh=bf_hi(a1H), gSh=bf_lo(s1H), pSh=bf_hi(s1H);
            sI1 += gAh-gSh; sII1 += gAh*gAh-gSh*gSh; sP1 += pAh-pSh; sIp1 += gAh*pAh-gSh*pSh;
        }
        float eI0=sI0, eII0=sII0, eP0=sP0, eIp0=sIp0;
        float eI1=sI1, eII1=sII1, eP1=sP1, eIp1=sIp1;
        // odd window y+1
        {
            float gA=bf_lo(a2M), pA=bf_hi(a2M), gS=bf_lo(s2M), pS=bf_hi(s2M);
            sI0 += gA-gS; sII0 += gA*gA-gS*gS; sP0 += pA-pS; sIp0 += gA*pA-gS*pS;
            float gAh=bf_lo(a2H), pAh=bf_hi(a2H), gSh=bf_lo(s2H), pSh=bf_hi(s2H);
            sI1 += gAh-gSh; sII1 += gAh*gAh-gSh*gSh; sP1 += pAh-pSh; sIp1 += gAh*pAh-gSh*pSh;
        }
        // prefetch next iteration's 4 row-pairs
        loadrow(y + 9,  a1M, a1H);
        loadrow(y - 6,  s1M, s1H);
        loadrow(y + 10, a2M, a2H);
        loadrow(y - 5,  s2M, s2H);
        // single packed exchange for both rows (ds_write_b128)
        Le[l] = make_float4(eI0, eII0, eP0, eIp0);
        Lo[l] = make_float4(sI0, sII0, sP0, sIp0);
        if (l < 14) {
            Le[64+l] = make_float4(eI1, eII1, eP1, eIp1);
            Lo[64+l] = make_float4(sI1, sII1, sP1, sIp1);
        }
        LDS_WAIT();
        float4 Te = tsum15v(&Le[l]);   // 15 x b128: all 4 quantities per read
        float4 To = tsum15v(&Lo[l]);
        WAVE_FENCE();   // keep next iter's ds_writes below these reads
        {
            float mI = Te.x*inv225, mP = Te.z*inv225;
            float va = (Te.w*inv225 - mI*mP) / (Te.y*inv225 - mI*mI + 1e-3f);
            abP[(size_t)y*WW + c0 + l] = packbf(va, mP - va*mI);
        }
        {
            float mI = To.x*inv225, mP = To.z*inv225;
            float va = (To.w*inv225 - mI*mP) / (To.y*inv225 - mI*mI + 1e-3f);
            abP[(size_t)(y+1)*WW + c0 + l] = packbf(va, mP - va*mI);
        }
    }
}

// ================= K3: two-phase — sliding box sums of (a,b) -> LDS means, then pure streaming emit ===========
// Phase 1: pair-row slide over ab only (no emit streams in the chain); means packed bf16 into mbuf.
// Phase 2: dependency-free fully-unrolled streaming of smoky/rho/out at copy-regime MLP.
__global__ __launch_bounds__(256, 4) void k3_final(
    const unsigned* __restrict__ abI,
    const float* __restrict__ smoky, const float* __restrict__ rho,
    float* __restrict__ out)
{
    __shared__ float4 ls[4][80];          // [wave][slot] slot=(a_e,b_e,a_o,b_o)
    __shared__ unsigned mbuf[4][16][64];  // [wave][row][col] packed bf16 (mean_a, mean_b)
    int nwg = gridDim.x;             // 1024
    int wg = (blockIdx.x & 7) * (nwg >> 3) + (blockIdx.x >> 3);
    int w = threadIdx.x >> 6, l = threadIdx.x & 63;
    int gw = wg * 4 + w;
    int img   = gw >> 8;
    int cg    = (gw >> 5) & 7;
    int strip = gw & 31;
    int y0 = strip * RS2;
    int c0 = cg * 64;
    const unsigned* abP = abI + (size_t)img * PLANE;
    const float* sP = smoky + (size_t)img * 3 * PLANE;
    const float* rP = rho   + (size_t)img * 3 * PLANE;
    float* oP = out + (size_t)img * 3 * PLANE;

    int col0 = c0 - 7 + l;
    int col1 = c0 + 57 + l;
    bool v0 = (col0 >= 0);
    bool v1 = (l < 14) && (col1 < WW);

    float sa0=0, sb0=0, sa1=0, sb1=0;

    auto loadrow = [&](int y, unsigned& u0, unsigned& u1) {
        int yc = min(max(y, 0), HH-1);
        const unsigned* r = abP + (size_t)yc * WW;
        unsigned a = 0u, b = 0u;
        if (v0) a = r[col0];
        if (v1) b = r[col1];
        bool rv = ((unsigned)y < (unsigned)HH);
        u0 = rv ? a : 0u;
        u1 = rv ? b : 0u;
    };

    for (int r = y0 - 8; r <= y0 + 6; ++r) {
        unsigned u0,u1; loadrow(r, u0,u1);
        sa0 += bf_lo(u0); sb0 += bf_hi(u0);
        sa1 += bf_lo(u1); sb1 += bf_hi(u1);
    }
    unsigned a1M,a1H, s1M,s1H, a2M,a2H, s2M,s2H;
    loadrow(y0 + 7, a1M, a1H);
    loadrow(y0 - 8, s1M, s1H);
    loadrow(y0 + 8, a2M, a2H);
    loadrow(y0 - 7, s2M, s2H);

    float4* L4 = &ls[w][0];
    unsigned (*mb)[64] = mbuf[w];
    const float inv225 = 1.0f/225.0f;

    // ---- Phase 1: box sums -> bf16 means in mbuf (no global streams in the chain) ----
    for (int y = y0; y < y0 + RS2; y += 2) {
        // even window y
        sa0 += bf_lo(a1M) - bf_lo(s1M);  sb0 += bf_hi(a1M) - bf_hi(s1M);
        sa1 += bf_lo(a1H) - bf_lo(s1H);  sb1 += bf_hi(a1H) - bf_hi(s1H);
        float ea0=sa0, eb0=sb0, ea1=sa1, eb1=sb1;
        // odd window y+1
        sa0 += bf_lo(a2M) - bf_lo(s2M);  sb0 += bf_hi(a2M) - bf_hi(s2M);
        sa1 += bf_lo(a2H) - bf_lo(s2H);  sb1 += bf_hi(a2H) - bf_hi(s2H);
        // prefetch next iteration's ab rows
        loadrow(y + 9,  a1M, a1H);
        loadrow(y - 6,  s1M, s1H);
        loadrow(y + 10, a2M, a2H);
        loadrow(y - 5,  s2M, s2H);
        // packed exchange: slot = (a_e, b_e, a_o, b_o)
        L4[l] = make_float4(ea0, eb0, sa0, sb0);
        if (l < 14) L4[64+l] = make_float4(ea1, eb1, sa1, sb1);
        LDS_WAIT();
        float4 T = tsum15v(&L4[l]);   // both rows, both quantities in one pass
        WAVE_FENCE();
        int i = y - y0;
        mb[i][l]   = packbf(T.x*inv225, T.y*inv225);
        mb[i+1][l] = packbf(T.z*inv225, T.w*inv225);
    }
    LDS_WAIT();   // mbuf writes complete; ordered before phase-2 reads

    // preload means into registers (static indices)
    unsigned mr[16];
    #pragma unroll
    for (int i = 0; i < 16; ++i) mr[i] = mb[i][l];
    LDS_WAIT();
    WAVE_FENCE();

    // ---- Phase 2: dependency-free streaming emit (fully unrolled, max MLP) ----
    const float inv11 = 1.0f/1.1f;
    const float third = 1.0f/3.0f;
    #pragma unroll
    for (int i = 0; i < 16; ++i) {
        size_t off = (size_t)(y0 + i)*WW + c0 + l;
        float s0 = sP[off], s1 = sP[off+PLANE], s2 = sP[off+2*PLANE];
        float r0 = rP[off], r1 = rP[off+PLANE], r2 = rP[off+2*PLANE];
        float g = (s0 + s1 + s2) * third;
        float f = (0.1f + bf_lo(mr[i])*g + bf_hi(mr[i])) * inv11;
        oP[off]          = s0 - f*(1.0f - r0);
        oP[off+PLANE]    = s1 - f*(1.0f - r1);
        oP[off+2*PLANE]  = s2 - f*(1.0f - r2);
    }
}

extern "C" void kernel_launch(void* const* d_in, const int* in_sizes, int n_in,
                              void* d_out, int out_size, void* d_ws, size_t ws_size,
                              hipStream_t stream) {
    const float* smoky = (const float*)d_in[0];
    const float* rho   = (const float*)d_in[1];
    float* out = (float*)d_out;
    const size_t P = (size_t)BATCH * PLANE;
    unsigned* gpbuf = (unsigned*)d_ws;        // packed bf16 (guide,p): P u32
    unsigned* abbuf = (unsigned*)d_ws + P;    // packed bf16 (a,b): P u32

    k1_guide_minpool<<<BATCH*64, 256, 0, stream>>>(smoky, gpbuf);
    k2_ab<<<BATCH*64, 256, 0, stream>>>(gpbuf, abbuf);
    k3_final<<<BATCH*64, 256, 0, stream>>>(abbuf, smoky, rho, out);
}

// Round 17
// 76.728 us; speedup vs baseline: 1.0139x; 1.0139x over previous
//
#include <hip/hip_runtime.h>

#define BATCH 16
#define HH 512
#define WW 512
#define PLANE (HH*WW)

// Compiler memory-order fences for wave-synchronous LDS exchange.
#define LDS_WAIT()   asm volatile("s_waitcnt lgkmcnt(0)" ::: "memory")
#define WAVE_FENCE() asm volatile("" ::: "memory")

// bf16 pair helpers: word = x in low 16 bits, y in high 16 bits
__device__ __forceinline__ float bf_lo(unsigned u) {
    union { unsigned u; float f; } c; c.u = u << 16; return c.f;
}
__device__ __forceinline__ float bf_hi(unsigned u) {
    union { unsigned u; float f; } c; c.u = u & 0xFFFF0000u; return c.f;
}
__device__ __forceinline__ unsigned f2bf(float f) {   // RTNE, returns low-16 bf16
    union { float f; unsigned u; } c; c.f = f;
    return (c.u + 0x7FFFu + ((c.u >> 16) & 1u)) >> 16;
}
__device__ __forceinline__ unsigned packbf(float x, float y) {
    return f2bf(x) | (f2bf(y) << 16);
}
__device__ __forceinline__ float min3f(float a, float b, float c) {
    return fminf(fminf(a, b), c);    // clang fuses to v_min3_f32
}
__device__ __forceinline__ float4 add4(float4 a, float4 b) {
    return make_float4(a.x+b.x, a.y+b.y, a.z+b.z, a.w+b.w);
}
// balanced-tree 15-tap sum over float4 slots: 15 x ds_read_b128 (one LDS instr
// returns all 4 packed quantities) instead of 60 x ds_read_b32.
__device__ __forceinline__ float4 tsum15v(const float4* p) {
    float4 s = add4(add4(add4(p[0],p[1]),add4(p[2],p[3])),
                    add4(add4(p[4],p[5]),add4(p[6],p[7])));
    float4 u = add4(add4(add4(p[8],p[9]),add4(p[10],p[11])),
                    add4(add4(p[12],p[13]),p[14]));
    return add4(s, u);
}

// ---------------- K1: guide (channel mean) + 15x15 replicate min-pool -> packed bf16 (g,p) ----------------
#define T1 64
#define HALO 7
#define LW (T1 + 2*HALO)   // 78

__global__ __launch_bounds__(256) void k1_guide_minpool(
    const float* __restrict__ smoky, unsigned* __restrict__ gp)
{
    __shared__ float dcp[LW*LW];          // per-pixel channel min, with replicate halo
    __shared__ float vmn[T1*LW];          // vertical 15-min
    __shared__ unsigned short gsh[T1*T1]; // guide (bf16) for interior
    int nwg = gridDim.x;             // 1024, divisible by 8
    int wg = (blockIdx.x & 7) * (nwg >> 3) + (blockIdx.x >> 3);  // XCD-chunked swizzle
    int img  = wg >> 6;              // 64 tiles per image
    int tile = wg & 63;
    int y0 = (tile >> 3) * T1;
    int x0 = (tile & 7) * T1;
    int t = threadIdx.x;
    const float* s0 = smoky + (size_t)img * 3 * PLANE;
    unsigned* gpl = gp + (size_t)img * PLANE;

    for (int i = t; i < LW*LW; i += 256) {
        int ly = i / LW, lx = i - ly * LW;
        int iy = y0 - HALO + ly, ix = x0 - HALO + lx;
        int cy = min(max(iy, 0), HH-1);
        int cx = min(max(ix, 0), WW-1);
        const float* bp = s0 + cy * WW + cx;
        float c0 = bp[0], c1 = bp[PLANE], c2 = bp[2*PLANE];
        dcp[i] = min3f(c0, c1, c2);
        if (ly >= HALO && ly < HALO+T1 && lx >= HALO && lx < HALO+T1)
            gsh[(ly-HALO)*T1 + (lx-HALO)] = (unsigned short)f2bf((c0 + c1 + c2) * (1.0f/3.0f));
    }
    __syncthreads();
    for (int i = t; i < T1*LW; i += 256) {
        int r = i / LW, c = i - r * LW;
        const float* q = &dcp[r*LW + c];
        float m = min3f(min3f(min3f(q[0*LW],q[1*LW],q[2*LW]),
                              min3f(q[3*LW],q[4*LW],q[5*LW]),
                              min3f(q[6*LW],q[7*LW],q[8*LW])),
                        min3f(q[9*LW],q[10*LW],q[11*LW]),
                        min3f(q[12*LW],q[13*LW],q[14*LW]));
        vmn[i] = m;
    }
    __syncthreads();
    for (int i = t; i < T1*T1; i += 256) {
        int r = i >> 6, c = i & 63;
        const float* q = &vmn[r*LW + c];
        float m = min3f(min3f(min3f(q[0],q[1],q[2]),
                              min3f(q[3],q[4],q[5]),
                              min3f(q[6],q[7],q[8])),
                        min3f(q[9],q[10],q[11]),
                        min3f(q[12],q[13],q[14]));
        gpl[(y0+r)*WW + x0 + c] = (unsigned)gsh[r*T1+c] | (f2bf(m) << 16);
    }
}

// ================= K2: pair-row sliding box sums, quantity-packed float4 exchange =================
#define RS2 16

__global__ __launch_bounds__(256) void k2_ab(
    const unsigned* __restrict__ gp, unsigned* __restrict__ abO)
{
    __shared__ float4 ls[4][2][80];   // [wave][row e/o][slot] slot=(sI,sII,sP,sIp)
    int nwg = gridDim.x;             // 1024
    int wg = (blockIdx.x & 7) * (nwg >> 3) + (blockIdx.x >> 3);
    int w = threadIdx.x >> 6, l = threadIdx.x & 63;
    int gw = wg * 4 + w;             // 0..4095
    int img   = gw >> 8;             // 256 waves per image
    int cg    = (gw >> 5) & 7;
    int strip = gw & 31;
    int y0 = strip * RS2;
    int c0 = cg * 64;
    const unsigned* gpP = gp + (size_t)img * PLANE;
    unsigned* abP = abO + (size_t)img * PLANE;

    int col0 = c0 - 7 + l;      // slot l
    int col1 = c0 + 57 + l;     // slot 64+l (lanes 0..13)
    bool v0 = (col0 >= 0);
    bool v1 = (l < 14) && (col1 < WW);

    float sI0=0,sII0=0,sP0=0,sIp0=0;
    float sI1=0,sII1=0,sP1=0,sIp1=0;

    auto loadrow = [&](int y, unsigned& u0, unsigned& u1) {
        int yc = min(max(y, 0), HH-1);
        const unsigned* r = gpP + (size_t)yc * WW;
        unsigned a = 0u, b = 0u;
        if (v0) a = r[col0];
        if (v1) b = r[col1];
        bool rv = ((unsigned)y < (unsigned)HH);
        u0 = rv ? a : 0u;
        u1 = rv ? b : 0u;
    };

    // warm-up: window(y0-1) = rows y0-8 .. y0+6
    for (int r = y0 - 8; r <= y0 + 6; ++r) {
        unsigned u0,u1; loadrow(r, u0,u1);
        float g0=bf_lo(u0), p0=bf_hi(u0), g1=bf_lo(u1), p1=bf_hi(u1);
        sI0+=g0; sII0+=g0*g0; sP0+=p0; sIp0+=g0*p0;
        sI1+=g1; sII1+=g1*g1; sP1+=p1; sIp1+=g1*p1;
    }
    unsigned a1M,a1H, s1M,s1H, a2M,a2H, s2M,s2H;
    loadrow(y0 + 7, a1M, a1H);   // add for even row
    loadrow(y0 - 8, s1M, s1H);   // sub for even row
    loadrow(y0 + 8, a2M, a2H);   // add for odd row
    loadrow(y0 - 7, s2M, s2H);   // sub for odd row

    float4* Le = &ls[w][0][0];
    float4* Lo = &ls[w][1][0];
    const float inv225 = 1.0f/225.0f;

    for (int y = y0; y < y0 + RS2; y += 2) {
        // even window y
        {
            float gA=bf_lo(a1M), pA=bf_hi(a1M), gS=bf_lo(s1M), pS=bf_hi(s1M);
            sI0 += gA-gS; sII0 += gA*gA-gS*gS; sP0 += pA-pS; sIp0 += gA*pA-gS*pS;
            float gAh=bf_lo(a1H), pAh=bf_hi(a1H), gSh=bf_lo(s1H), pSh=bf_hi(s1H);
            sI1 += gAh-gSh; sII1 += gAh*gAh-gSh*gSh; sP1 += pAh-pSh; sIp1 += gAh*pAh-gSh*pSh;
        }
        float eI0=sI0, eII0=sII0, eP0=sP0, eIp0=sIp0;
        float eI1=sI1, eII1=sII1, eP1=sP1, eIp1=sIp1;
        // odd window y+1
        {
            float gA=bf_lo(a2M), pA=bf_hi(a2M), gS=bf_lo(s2M), pS=bf_hi(s2M);
            sI0 += gA-gS; sII0 += gA*gA-gS*gS; sP0 += pA-pS; sIp0 += gA*pA-gS*pS;
            float gAh=bf_lo(a2H), pAh=bf_hi(a2H), gSh=bf_lo(s2H), pSh=bf_hi(s2H);
            sI1 += gAh-gSh; sII1 += gAh*gAh-gSh*gSh; sP1 += pAh-pSh; sIp1 += gAh*pAh-gSh*pSh;
        }
        // prefetch next iteration's 4 row-pairs
        loadrow(y + 9,  a1M, a1H);
        loadrow(y - 6,  s1M, s1H);
        loadrow(y + 10, a2M, a2H);
        loadrow(y - 5,  s2M, s2H);
        // single packed exchange for both rows (ds_write_b128)
        Le[l] = make_float4(eI0, eII0, eP0, eIp0);
        Lo[l] = make_float4(sI0, sII0, sP0, sIp0);
        if (l < 14) {
            Le[64+l] = make_float4(eI1, eII1, eP1, eIp1);
            Lo[64+l] = make_float4(sI1, sII1, sP1, sIp1);
        }
        LDS_WAIT();
        float4 Te = tsum15v(&Le[l]);   // 15 x b128: all 4 quantities per read
        float4 To = tsum15v(&Lo[l]);
        WAVE_FENCE();   // keep next iter's ds_writes below these reads
        {
            float mI = Te.x*inv225, mP = Te.z*inv225;
            float va = (Te.w*inv225 - mI*mP) / (Te.y*inv225 - mI*mI + 1e-3f);
            abP[(size_t)y*WW + c0 + l] = packbf(va, mP - va*mI);
        }
        {
            float mI = To.x*inv225, mP = To.z*inv225;
            float va = (To.w*inv225 - mI*mP) / (To.y*inv225 - mI*mI + 1e-3f);
            abP[(size_t)(y+1)*WW + c0 + l] = packbf(va, mP - va*mI);
        }
    }
}

// ================= K3: pair-row sliding box sums of (a,b), float4-packed exchange =================
// slot = (a_even, b_even, a_odd, b_odd): one 15-tap b128 pass serves both rows.
__global__ __launch_bounds__(256) void k3_final(
    const unsigned* __restrict__ abI,
    const float* __restrict__ smoky, const float* __restrict__ rho,
    float* __restrict__ out)
{
    __shared__ float4 ls[4][80];     // [wave][slot]
    int nwg = gridDim.x;             // 1024
    int wg = (blockIdx.x & 7) * (nwg >> 3) + (blockIdx.x >> 3);
    int w = threadIdx.x >> 6, l = threadIdx.x & 63;
    int gw = wg * 4 + w;
    int img   = gw >> 8;
    int cg    = (gw >> 5) & 7;
    int strip = gw & 31;
    int y0 = strip * RS2;
    int c0 = cg * 64;
    const unsigned* abP = abI + (size_t)img * PLANE;
    const float* sP = smoky + (size_t)img * 3 * PLANE;
    const float* rP = rho   + (size_t)img * 3 * PLANE;
    float* oP = out + (size_t)img * 3 * PLANE;

    int col0 = c0 - 7 + l;
    int col1 = c0 + 57 + l;
    bool v0 = (col0 >= 0);
    bool v1 = (l < 14) && (col1 < WW);

    float sa0=0, sb0=0, sa1=0, sb1=0;

    auto loadrow = [&](int y, unsigned& u0, unsigned& u1) {
        int yc = min(max(y, 0), HH-1);
        const unsigned* r = abP + (size_t)yc * WW;
        unsigned a = 0u, b = 0u;
        if (v0) a = r[col0];
        if (v1) b = r[col1];
        bool rv = ((unsigned)y < (unsigned)HH);
        u0 = rv ? a : 0u;
        u1 = rv ? b : 0u;
    };

    for (int r = y0 - 8; r <= y0 + 6; ++r) {
        unsigned u0,u1; loadrow(r, u0,u1);
        sa0 += bf_lo(u0); sb0 += bf_hi(u0);
        sa1 += bf_lo(u1); sb1 += bf_hi(u1);
    }
    unsigned a1M,a1H, s1M,s1H, a2M,a2H, s2M,s2H;
    loadrow(y0 + 7, a1M, a1H);
    loadrow(y0 - 8, s1M, s1H);
    loadrow(y0 + 8, a2M, a2H);
    loadrow(y0 - 7, s2M, s2H);

    // prefetched emit operands for the row pair (smoky/rho), branchless clamp
    float esA0,esA1,esA2, erA0,erA1,erA2;   // even row
    float esB0,esB1,esB2, erB0,erB1,erB2;   // odd row
    int yend = y0 + RS2;
    auto loademit = [&](int y,
                        float& e0, float& e1, float& e2,
                        float& r0, float& r1, float& r2) {
        int e = min(y, yend - 1);
        size_t off = (size_t)e*WW + c0 + l;
        e0 = sP[off]; e1 = sP[off+PLANE]; e2 = sP[off+2*PLANE];
        r0 = rP[off]; r1 = rP[off+PLANE]; r2 = rP[off+2*PLANE];
    };
    loademit(y0,     esA0,esA1,esA2, erA0,erA1,erA2);
    loademit(y0 + 1, esB0,esB1,esB2, erB0,erB1,erB2);

    float4* L4 = &ls[w][0];
    const float inv225 = 1.0f/225.0f;
    const float inv11  = 1.0f/1.1f;
    const float third  = 1.0f/3.0f;
    for (int y = y0; y < yend; y += 2) {
        // even window y
        sa0 += bf_lo(a1M) - bf_lo(s1M);  sb0 += bf_hi(a1M) - bf_hi(s1M);
        sa1 += bf_lo(a1H) - bf_lo(s1H);  sb1 += bf_hi(a1H) - bf_hi(s1H);
        float ea0=sa0, eb0=sb0, ea1=sa1, eb1=sb1;
        // odd window y+1
        sa0 += bf_lo(a2M) - bf_lo(s2M);  sb0 += bf_hi(a2M) - bf_hi(s2M);
        sa1 += bf_lo(a2H) - bf_lo(s2H);  sb1 += bf_hi(a2H) - bf_hi(s2H);
        // capture emit operands
        float cA0=esA0, cA1=esA1, cA2=esA2, dA0=erA0, dA1=erA1, dA2=erA2;
        float cB0=esB0, cB1=esB1, cB2=esB2, dB0=erB0, dB1=erB1, dB2=erB2;
        // prefetch next iteration
        loadrow(y + 9,  a1M, a1H);
        loadrow(y - 6,  s1M, s1H);
        loadrow(y + 10, a2M, a2H);
        loadrow(y - 5,  s2M, s2H);
        loademit(y + 2, esA0,esA1,esA2, erA0,erA1,erA2);
        loademit(y + 3, esB0,esB1,esB2, erB0,erB1,erB2);
        // single packed exchange: slot = (a_e, b_e, a_o, b_o)
        L4[l] = make_float4(ea0, eb0, sa0, sb0);
        if (l < 14) L4[64+l] = make_float4(ea1, eb1, sa1, sb1);
        LDS_WAIT();
        float4 T = tsum15v(&L4[l]);   // both rows, both quantities in one pass
        WAVE_FENCE();
        // emit even row
        {
            float g = (cA0 + cA1 + cA2) * third;
            float f = (0.1f + T.x*inv225*g + T.y*inv225) * inv11;
            size_t off = (size_t)y*WW + c0 + l;
            oP[off]          = cA0 - f*(1.0f - dA0);
            oP[off+PLANE]    = cA1 - f*(1.0f - dA1);
            oP[off+2*PLANE]  = cA2 - f*(1.0f - dA2);
        }
        // emit odd row
        {
            float g = (cB0 + cB1 + cB2) * third;
            float f = (0.1f + T.z*inv225*g + T.w*inv225) * inv11;
            size_t off = (size_t)(y+1)*WW + c0 + l;
            oP[off]          = cB0 - f*(1.0f - dB0);
            oP[off+PLANE]    = cB1 - f*(1.0f - dB1);
            oP[off+2*PLANE]  = cB2 - f*(1.0f - dB2);
        }
    }
}

extern "C" void kernel_launch(void* const* d_in, const int* in_sizes, int n_in,
                              void* d_out, int out_size, void* d_ws, size_t ws_size,
                              hipStream_t stream) {
    const float* smoky = (const float*)d_in[0];
    const float* rho   = (const float*)d_in[1];
    float* out = (float*)d_out;
    const size_t P = (size_t)BATCH * PLANE;
    unsigned* gpbuf = (unsigned*)d_ws;        // packed bf16 (guide,p): P u32
    unsigned* abbuf = (unsigned*)d_ws + P;    // packed bf16 (a,b): P u32

    k1_guide_minpool<<<BATCH*64, 256, 0, stream>>>(smoky, gpbuf);
    k2_ab<<<BATCH*64, 256, 0, stream>>>(gpbuf, abbuf);
    k3_final<<<BATCH*64, 256, 0, stream>>>(abbuf, smoky, rho, out);
}